// Round 11
// baseline (78.614 us; speedup 1.0000x reference)
//
#include <hip/hip_runtime.h>

#define NN 2048
#define KK 32

typedef __attribute__((ext_vector_type(4))) float f32x4;

// workspace (bytes):
//  u_pk   : [2048 j][32 b][32 k][8 zp] u32 (bf16 z-pairs) 64 MiB @ 0
//  t_part4: [32 jsl][16384] f32                            2 MiB @ 67108864
//  t      : [32 b][32 k][16 z] f32                        64 KiB @ 69206016
//  s_part : [32 b][64 jc][512] f32                         4 MiB @ 69271552
#define WS_U     0UL
#define WS_TP4   67108864UL
#define WS_T     69206016UL
#define WS_SPART 69271552UL
#define WS_NEED  73465856UL

__device__ __forceinline__ float bf_lo(unsigned v) { return __uint_as_float(v << 16); }
__device__ __forceinline__ float bf_hi(unsigned v) { return __uint_as_float(v & 0xffff0000u); }
__device__ __forceinline__ unsigned pack_bf16(float a, float b) {
    unsigned ua = __float_as_uint(a), ub = __float_as_uint(b);
    return ((ua + 0x8000u) >> 16) | ((ub + 0x8000u) & 0xffff0000u);
}

// ---------------- kU: u = x @ w, all-coalesced streaming (VALU FMA) ---------
// grid 512 (2 blocks/CU, 4 j each), block 512.
// Per j: stage w (dwordx4, 1KB/instr) + x -> LDS; compute thread=(k,zq,bh):
// 8b x 4z x 16i FMA from LDS; pack bf16 pairs -> u_tr LDS [b][264];
// store: 64 consecutive lanes x uint4 = contiguous 1KB per instruction.
__global__ __launch_bounds__(512)
void kU(const float* __restrict__ x, const float* __restrict__ w,
        unsigned* __restrict__ u_pk)
{
    __shared__ float    w_lds[32 * 257];    // [k][257] pad -> 2-way max
    __shared__ float    x_lds[32][16];
    __shared__ unsigned u_tr[32 * 264];     // [b][264] pad
    const int tid = threadIdx.x;
    const int k   = tid & 31;
    const int zq  = (tid >> 5) & 3;
    const int bh  = tid >> 7;               // 0..3
    const int j0  = blockIdx.x * 4;

#pragma unroll 1
    for (int jj = 0; jj < 4; ++jj) {
        const int j = j0 + jj;

        // ---- stage w (32KB) + x (2KB), fully coalesced ----
        {
            const int kk = tid >> 4, c = tid & 15;
            const float4* wg = reinterpret_cast<const float4*>(
                w + ((size_t)kk * NN + j) * 256);
            float4 v0 = wg[c];
            float4 v1 = wg[16 + c];
            float4 v2 = wg[32 + c];
            float4 v3 = wg[48 + c];
            *reinterpret_cast<float4*>(&w_lds[kk * 257 +   0 + c * 4]) = v0;
            *reinterpret_cast<float4*>(&w_lds[kk * 257 +  64 + c * 4]) = v1;
            *reinterpret_cast<float4*>(&w_lds[kk * 257 + 128 + c * 4]) = v2;
            *reinterpret_cast<float4*>(&w_lds[kk * 257 + 192 + c * 4]) = v3;
            x_lds[kk][c] = x[((size_t)kk * NN + j) * 16 + c];
        }
        __syncthreads();

        // ---- compute: w[16i][4z] in regs, x broadcast from LDS ----
        float wr[16][4];
#pragma unroll
        for (int i = 0; i < 16; ++i)
            *reinterpret_cast<float4*>(wr[i]) =
                *reinterpret_cast<const float4*>(&w_lds[k * 257 + i * 16 + zq * 4]);

#pragma unroll
        for (int b8 = 0; b8 < 8; ++b8) {
            const int b = bh * 8 + b8;
            float a0 = 0.f, a1 = 0.f, a2 = 0.f, a3 = 0.f;
#pragma unroll
            for (int iq = 0; iq < 4; ++iq) {
                float4 xv = *reinterpret_cast<const float4*>(&x_lds[b][iq * 4]);
#pragma unroll
                for (int ii = 0; ii < 4; ++ii) {
                    const float xs = (ii == 0) ? xv.x : (ii == 1) ? xv.y
                                   : (ii == 2) ? xv.z : xv.w;
                    a0 = fmaf(xs, wr[iq * 4 + ii][0], a0);
                    a1 = fmaf(xs, wr[iq * 4 + ii][1], a1);
                    a2 = fmaf(xs, wr[iq * 4 + ii][2], a2);
                    a3 = fmaf(xs, wr[iq * 4 + ii][3], a3);
                }
            }
            uint2 o;
            o.x = pack_bf16(a0, a1);
            o.y = pack_bf16(a2, a3);
            *reinterpret_cast<uint2*>(&u_tr[b * 264 + k * 8 + zq * 2]) = o;
        }
        __syncthreads();

        // ---- store: 4 x dwordx4, each instr = 64 lanes x 16B contiguous ----
        {
            const int lane = tid & 63;            // col quad
            const int bb   = tid >> 6;            // 0..7
            uint4* dst = reinterpret_cast<uint4*>(u_pk) + (size_t)j * 2048;
#pragma unroll
            for (int r = 0; r < 4; ++r) {
                const int b = r * 8 + bb;
                uint4 v = *reinterpret_cast<const uint4*>(&u_tr[b * 264 + lane * 4]);
                dst[b * 64 + lane] = v;
            }
        }
        __syncthreads();
    }
}

// ---------------- kt_u: t partials = col-sums of u_pk (uint4 loads) ---------
// grid 1024 (= 32 col-chunks x 32 j-slices), block 1024: js = tid>>6, c4 = tid&63.
__global__ __launch_bounds__(1024)
void kt_u(const unsigned* __restrict__ u_pk, float* __restrict__ t_part4)
{
    __shared__ float red[16][64][8];   // 32KB
    const int tid = threadIdx.x;
    const int js = tid >> 6, c4 = tid & 63;
    const int cch = blockIdx.x & 31, jsl = blockIdx.x >> 5;

    const uint4* up = reinterpret_cast<const uint4*>(u_pk);
    float a[8];
#pragma unroll
    for (int e = 0; e < 8; ++e) a[e] = 0.f;
#pragma unroll
    for (int q = 0; q < 4; ++q) {
        const int j = jsl * 64 + q * 16 + js;
        uint4 v = up[(size_t)j * 2048 + cch * 64 + c4];
        a[0] += bf_lo(v.x); a[1] += bf_hi(v.x);
        a[2] += bf_lo(v.y); a[3] += bf_hi(v.y);
        a[4] += bf_lo(v.z); a[5] += bf_hi(v.z);
        a[6] += bf_lo(v.w); a[7] += bf_hi(v.w);
    }
#pragma unroll
    for (int e = 0; e < 8; ++e) red[js][c4][e] = a[e];
    __syncthreads();
    if (tid < 512) {
        const int cc = tid >> 3, e = tid & 7;
        float s = 0.f;
#pragma unroll
        for (int r = 0; r < 16; ++r) s += red[r][cc][e];
        t_part4[(size_t)jsl * 16384 + (cch * 64 + cc) * 8 + e] = s;
    }
}

// ---------------- kt2b: reduce 32 slices -> t[b][k][z] ----------------------
__global__ __launch_bounds__(256)
void kt2b(const float* __restrict__ t_part4, float* __restrict__ t)
{
    const int idx4 = blockIdx.x * 256 + threadIdx.x;   // 4096 f32x4
    const f32x4* P = reinterpret_cast<const f32x4*>(t_part4);
    f32x4 a0 = (f32x4){0,0,0,0}, a1 = a0, a2 = a0, a3 = a0;
#pragma unroll
    for (int sl = 0; sl < 32; sl += 4) {
        a0 += P[(size_t)(sl + 0) * 4096 + idx4];
        a1 += P[(size_t)(sl + 1) * 4096 + idx4];
        a2 += P[(size_t)(sl + 2) * 4096 + idx4];
        a3 += P[(size_t)(sl + 3) * 4096 + idx4];
    }
    reinterpret_cast<f32x4*>(t)[idx4] = (a0 + a1) + (a2 + a3);
}

// ---------------- kB2: logits + softmax + bias + s-partials (VALU only) -----
// grid 2048 (= 32 b * 64 jc), block 256: k = tid&31, jl = tid>>5.
__global__ __launch_bounds__(256)
void kB2(const unsigned* __restrict__ u_pk, const float* __restrict__ t,
         const float* __restrict__ bias, float* __restrict__ s_part)
{
    __shared__ float lc_lds[32][33];
    __shared__ float s_lds[8][32][16];
    const int tid = threadIdx.x;
    const int k   = tid & 31;
    const int jl  = tid >> 5;
    const int b   = blockIdx.x >> 6;
    const int jc  = blockIdx.x & 63;

    float tr[16];
    const float4* tp = reinterpret_cast<const float4*>(t + ((size_t)b * KK + k) * 16);
#pragma unroll
    for (int q = 0; q < 4; ++q) {
        float4 v = tp[q];
        tr[4 * q + 0] = v.x; tr[4 * q + 1] = v.y; tr[4 * q + 2] = v.z; tr[4 * q + 3] = v.w;
    }

    uint4 ua[4], ud[4];
#pragma unroll
    for (int jj = 0; jj < 4; ++jj) {
        const int jL = jj * 8 + jl;
        const int jg = jc * 32 + jL;
        const uint4* up = reinterpret_cast<const uint4*>(u_pk)
                        + (((size_t)jg * 32 + b) * 32 + k) * 2;
        ua[jj] = up[0]; ud[jj] = up[1];
        float a0 = 0.f, a1 = 0.f;
        a0 = fmaf(bf_lo(ua[jj].x), tr[0],  a0); a1 = fmaf(bf_hi(ua[jj].x), tr[1],  a1);
        a0 = fmaf(bf_lo(ua[jj].y), tr[2],  a0); a1 = fmaf(bf_hi(ua[jj].y), tr[3],  a1);
        a0 = fmaf(bf_lo(ua[jj].z), tr[4],  a0); a1 = fmaf(bf_hi(ua[jj].z), tr[5],  a1);
        a0 = fmaf(bf_lo(ua[jj].w), tr[6],  a0); a1 = fmaf(bf_hi(ua[jj].w), tr[7],  a1);
        a0 = fmaf(bf_lo(ud[jj].x), tr[8],  a0); a1 = fmaf(bf_hi(ud[jj].x), tr[9],  a1);
        a0 = fmaf(bf_lo(ud[jj].y), tr[10], a0); a1 = fmaf(bf_hi(ud[jj].y), tr[11], a1);
        a0 = fmaf(bf_lo(ud[jj].z), tr[12], a0); a1 = fmaf(bf_hi(ud[jj].z), tr[13], a1);
        a0 = fmaf(bf_lo(ud[jj].w), tr[14], a0); a1 = fmaf(bf_hi(ud[jj].w), tr[15], a1);
        lc_lds[jL][k] = a0 + a1;
    }
    __syncthreads();

    {
        const int jq = tid >> 3, kq = tid & 7;
        float lv[4];
#pragma unroll
        for (int m = 0; m < 4; ++m) lv[m] = lc_lds[jq][kq * 4 + m];
        float pm = fmaxf(fmaxf(lv[0], lv[1]), fmaxf(lv[2], lv[3]));
        pm = fmaxf(pm, __shfl_xor(pm, 1));
        pm = fmaxf(pm, __shfl_xor(pm, 2));
        pm = fmaxf(pm, __shfl_xor(pm, 4));
        float ev[4], ps = 0.f;
#pragma unroll
        for (int m = 0; m < 4; ++m) { ev[m] = __expf((lv[m] - pm) * 0.25f); ps += ev[m]; }
        ps += __shfl_xor(ps, 1);
        ps += __shfl_xor(ps, 2);
        ps += __shfl_xor(ps, 4);
        const float inv = 1.f / ps;
        const int jg = jc * 32 + jq;
#pragma unroll
        for (int m = 0; m < 4; ++m)
            lv[m] = ev[m] * inv + bias[(size_t)(kq * 4 + m) * NN + jg];
        __syncthreads();
#pragma unroll
        for (int m = 0; m < 4; ++m) lc_lds[jq][kq * 4 + m] = lv[m];
    }
    __syncthreads();

    float sacc[16];
#pragma unroll
    for (int z = 0; z < 16; ++z) sacc[z] = 0.f;
#pragma unroll
    for (int jj = 0; jj < 4; ++jj) {
        const float cv = lc_lds[jj * 8 + jl][k];
        const uint4 a = ua[jj], d = ud[jj];
        sacc[0]  = fmaf(cv, bf_lo(a.x), sacc[0]);  sacc[1]  = fmaf(cv, bf_hi(a.x), sacc[1]);
        sacc[2]  = fmaf(cv, bf_lo(a.y), sacc[2]);  sacc[3]  = fmaf(cv, bf_hi(a.y), sacc[3]);
        sacc[4]  = fmaf(cv, bf_lo(a.z), sacc[4]);  sacc[5]  = fmaf(cv, bf_hi(a.z), sacc[5]);
        sacc[6]  = fmaf(cv, bf_lo(a.w), sacc[6]);  sacc[7]  = fmaf(cv, bf_hi(a.w), sacc[7]);
        sacc[8]  = fmaf(cv, bf_lo(d.x), sacc[8]);  sacc[9]  = fmaf(cv, bf_hi(d.x), sacc[9]);
        sacc[10] = fmaf(cv, bf_lo(d.y), sacc[10]); sacc[11] = fmaf(cv, bf_hi(d.y), sacc[11]);
        sacc[12] = fmaf(cv, bf_lo(d.z), sacc[12]); sacc[13] = fmaf(cv, bf_hi(d.z), sacc[13]);
        sacc[14] = fmaf(cv, bf_lo(d.w), sacc[14]); sacc[15] = fmaf(cv, bf_hi(d.w), sacc[15]);
    }

#pragma unroll
    for (int q = 0; q < 4; ++q)
        *reinterpret_cast<float4*>(&s_lds[jl][k][q * 4]) =
            make_float4(sacc[q * 4], sacc[q * 4 + 1], sacc[q * 4 + 2], sacc[q * 4 + 3]);
    __syncthreads();
    {
        const int kk = tid >> 3, zp = tid & 7;
        float2 o; o.x = 0.f; o.y = 0.f;
#pragma unroll
        for (int l2 = 0; l2 < 8; ++l2) {
            o.x += s_lds[l2][kk][2 * zp];
            o.y += s_lds[l2][kk][2 * zp + 1];
        }
        reinterpret_cast<float2*>(s_part)[((size_t)b * 64 + jc) * 256 + kk * 8 + zp] = o;
    }
}

// ---------------- k4: reduce jc slices + squash (float4) --------------------
__global__ __launch_bounds__(256)
void k4_squash(const float* __restrict__ s_part, float* __restrict__ out)
{
    const int idx4 = blockIdx.x * 256 + threadIdx.x;   // 4096 float4s
    const int b = idx4 >> 7, loc4 = idx4 & 127;        // loc4 = k*4 + zq
    const float4* p = reinterpret_cast<const float4*>(s_part) + (size_t)b * 8192 + loc4;
    float4 s = make_float4(0.f, 0.f, 0.f, 0.f);
#pragma unroll 8
    for (int jc = 0; jc < 64; ++jc) {
        float4 v = p[jc * 128];
        s.x += v.x; s.y += v.y; s.z += v.z; s.w += v.w;
    }
    float ss = s.x * s.x + s.y * s.y + s.z * s.z + s.w * s.w;
    ss += __shfl_xor(ss, 1);   // lanes zq 0..3 of same (b,k)
    ss += __shfl_xor(ss, 2);
    const float n = sqrtf(ss);
    const float sc = (1.f - 1.f / (__expf(n) + 1e-20f)) / (n + 1e-20f);
    float4 o; o.x = s.x * sc; o.y = s.y * sc; o.z = s.z * sc; o.w = s.w * sc;
    reinterpret_cast<float4*>(out)[idx4] = o;
}

// sentinel if workspace too small
__global__ void k_sentinel(float* __restrict__ out)
{
    out[blockIdx.x * 256 + threadIdx.x] = 12345.0f;
}

extern "C" void kernel_launch(void* const* d_in, const int* in_sizes, int n_in,
                              void* d_out, int out_size, void* d_ws, size_t ws_size,
                              hipStream_t stream)
{
    const float* x    = (const float*)d_in[0];
    const float* w    = (const float*)d_in[1];
    const float* bias = (const float*)d_in[2];
    float* out        = (float*)d_out;

    char* ws = (char*)d_ws;
    if (ws_size < WS_NEED) {
        k_sentinel<<<dim3(64), dim3(256), 0, stream>>>(out);
        return;
    }
    unsigned* u_pk   = (unsigned*)(ws + WS_U);
    float*    t_part4= (float*)(ws + WS_TP4);
    float*    t      = (float*)(ws + WS_T);
    float*    s_part = (float*)(ws + WS_SPART);

    kU       <<<dim3(512),  dim3(512),  0, stream>>>(x, w, u_pk);
    kt_u     <<<dim3(1024), dim3(1024), 0, stream>>>(u_pk, t_part4);
    kt2b     <<<dim3(16),   dim3(256),  0, stream>>>(t_part4, t);
    kB2      <<<dim3(2048), dim3(256),  0, stream>>>(u_pk, t, bias, s_part);
    k4_squash<<<dim3(16),   dim3(256),  0, stream>>>(s_part, out);
}

// Round 12
// 69.731 us; speedup vs baseline: 1.1274x; 1.1274x over previous
//
#include <hip/hip_runtime.h>

#define NN 2048
#define KK 32

typedef __attribute__((ext_vector_type(8))) short short8;   // 8 x bf16
typedef __attribute__((ext_vector_type(4))) float f32x4;

// workspace (bytes):
//  u_pk   : [2048 j][32 b][32 k][8 zp] u32 (bf16 z-pairs) 64 MiB @ 0
//  t_part4: [32 jsl][16384] f32                            2 MiB @ 67108864
//  t      : [32 b][32 k][16 z] f32                        64 KiB @ 69206016
//  s_part : [32 b][64 jc][512] f32                         4 MiB @ 69271552
#define WS_U     0UL
#define WS_TP4   67108864UL
#define WS_T     69206016UL
#define WS_SPART 69271552UL
#define WS_NEED  73465856UL

__device__ __forceinline__ float bf_lo(unsigned v) { return __uint_as_float(v << 16); }
__device__ __forceinline__ float bf_hi(unsigned v) { return __uint_as_float(v & 0xffff0000u); }
__device__ __forceinline__ unsigned pack_bf16(float a, float b) {
    unsigned ua = __float_as_uint(a), ub = __float_as_uint(b);
    return ((ua + 0x8000u) >> 16) | ((ub + 0x8000u) & 0xffff0000u);
}
__device__ __forceinline__ short8 pack8(const float* r) {
    short8 o;
#pragma unroll
    for (int e = 0; e < 8; ++e)
        o[e] = (short)(unsigned short)((__float_as_uint(r[e]) + 0x8000u) >> 16);
    return o;
}
__device__ __forceinline__ short8 sel8(bool keep, short8 v) {
    union { short8 s; unsigned u[4]; } a, b;
    a.s = v;
#pragma unroll
    for (int i = 0; i < 4; ++i) b.u[i] = keep ? a.u[i] : 0u;
    return b.s;
}

// ---------------- kA3: u = x @ w via MFMA, occupancy-first -------------------
// grid 2048 (1 j / block), block 256 = 4 waves (no __syncthreads anywhere).
// Wave wv owns k = wv*8..+8. MFMA 16x16x32: A = w (M=z), B = x (N=b);
// K half-filled (i = (g&1)*8+e; lanes g>=2 zeroed via sel8 on x-operand).
// Per-wave LDS transpose (19 KB/block, stride-19 pad ~2-way) -> uint4 stores
// of 128B segments, layout [j][b][k][zp] (consumer-proven).
__global__ __launch_bounds__(256)
void kA3(const float* __restrict__ x, const float* __restrict__ w,
         unsigned* __restrict__ u_pk)
{
    __shared__ uint2 xfer[4][32][19];
    const int tid = threadIdx.x;
    const int wv = tid >> 6, l = tid & 63;
    const int c16 = l & 15, g = l >> 4;
    const bool klo = (g < 2);
    const int j = blockIdx.x;

    // A fragments (w): k = wv*8 + q; i = (g&1)*8 + e (g>=2 mirrors g<2, zeroed later)
    short8 Wf[8];
#pragma unroll
    for (int q = 0; q < 8; ++q) {
        const int k = wv * 8 + q;
        const float* wp = w + ((size_t)k * NN + j) * 256 + (g & 1) * 128 + c16;
        float br[8];
#pragma unroll
        for (int e = 0; e < 8; ++e) br[e] = wp[e * 16];
        Wf[q] = pack8(br);
    }
    // B fragments (x): b = bn*16 + c16; zero lanes g>=2 (kills the mirrored K half)
    short8 Xf[2];
#pragma unroll
    for (int bn = 0; bn < 2; ++bn) {
        const float* xp = x + ((size_t)(bn * 16 + c16) * NN + j) * 16 + (g & 1) * 8;
        float ar[8];
        float4 v0 = *reinterpret_cast<const float4*>(xp);
        float4 v1 = *reinterpret_cast<const float4*>(xp + 4);
        ar[0]=v0.x; ar[1]=v0.y; ar[2]=v0.z; ar[3]=v0.w;
        ar[4]=v1.x; ar[5]=v1.y; ar[6]=v1.z; ar[7]=v1.w;
        Xf[bn] = sel8(klo, pack8(ar));
    }

    uint4* dst = reinterpret_cast<uint4*>(u_pk) + (size_t)j * 2048;
#pragma unroll
    for (int r = 0; r < 2; ++r) {
        // MFMA 4 k x 2 bn -> pack -> per-wave LDS
        const f32x4 zero = (f32x4){0.f, 0.f, 0.f, 0.f};
#pragma unroll
        for (int dk = 0; dk < 4; ++dk) {
#pragma unroll
            for (int bn = 0; bn < 2; ++bn) {
                f32x4 C = __builtin_amdgcn_mfma_f32_16x16x32_bf16(
                    Wf[r * 4 + dk], Xf[bn], zero, 0, 0, 0);
                uint2 o;
                o.x = pack_bf16(C[0], C[1]);   // z = g*4, g*4+1
                o.y = pack_bf16(C[2], C[3]);   // z = g*4+2, g*4+3
                xfer[wv][bn * 16 + c16][dk * 4 + g] = o;
            }
        }
        // read back in store order (same-wave DS ordering; compiler waits lgkm)
#pragma unroll
        for (int i = 0; i < 4; ++i) {
            const int f   = i * 64 + l;        // uint4 index within wave tile
            const int b   = f >> 3;
            const int dk  = (f >> 1) & 3;
            const int zpq = f & 1;
            uint2 e0 = xfer[wv][b][dk * 4 + zpq * 2];
            uint2 e1 = xfer[wv][b][dk * 4 + zpq * 2 + 1];
            uint4 v; v.x = e0.x; v.y = e0.y; v.z = e1.x; v.w = e1.y;
            dst[(size_t)b * 64 + (wv * 8 + r * 4 + dk) * 2 + zpq] = v;
        }
    }
}

// ---------------- kt_u: t partials = col-sums of u_pk (uint4 loads) ---------
// grid 1024 (= 32 col-chunks x 32 j-slices), block 1024: js = tid>>6, c4 = tid&63.
__global__ __launch_bounds__(1024)
void kt_u(const unsigned* __restrict__ u_pk, float* __restrict__ t_part4)
{
    __shared__ float red[16][64][8];   // 32KB
    const int tid = threadIdx.x;
    const int js = tid >> 6, c4 = tid & 63;
    const int cch = blockIdx.x & 31, jsl = blockIdx.x >> 5;

    const uint4* up = reinterpret_cast<const uint4*>(u_pk);
    float a[8];
#pragma unroll
    for (int e = 0; e < 8; ++e) a[e] = 0.f;
#pragma unroll
    for (int q = 0; q < 4; ++q) {
        const int j = jsl * 64 + q * 16 + js;
        uint4 v = up[(size_t)j * 2048 + cch * 64 + c4];
        a[0] += bf_lo(v.x); a[1] += bf_hi(v.x);
        a[2] += bf_lo(v.y); a[3] += bf_hi(v.y);
        a[4] += bf_lo(v.z); a[5] += bf_hi(v.z);
        a[6] += bf_lo(v.w); a[7] += bf_hi(v.w);
    }
#pragma unroll
    for (int e = 0; e < 8; ++e) red[js][c4][e] = a[e];
    __syncthreads();
    if (tid < 512) {
        const int cc = tid >> 3, e = tid & 7;
        float s = 0.f;
#pragma unroll
        for (int r = 0; r < 16; ++r) s += red[r][cc][e];
        t_part4[(size_t)jsl * 16384 + (cch * 64 + cc) * 8 + e] = s;
    }
}

// ---------------- kt2b: reduce 32 slices -> t[b][k][z] ----------------------
__global__ __launch_bounds__(256)
void kt2b(const float* __restrict__ t_part4, float* __restrict__ t)
{
    const int idx4 = blockIdx.x * 256 + threadIdx.x;   // 4096 f32x4
    const f32x4* P = reinterpret_cast<const f32x4*>(t_part4);
    f32x4 a0 = (f32x4){0,0,0,0}, a1 = a0, a2 = a0, a3 = a0;
#pragma unroll
    for (int sl = 0; sl < 32; sl += 4) {
        a0 += P[(size_t)(sl + 0) * 4096 + idx4];
        a1 += P[(size_t)(sl + 1) * 4096 + idx4];
        a2 += P[(size_t)(sl + 2) * 4096 + idx4];
        a3 += P[(size_t)(sl + 3) * 4096 + idx4];
    }
    reinterpret_cast<f32x4*>(t)[idx4] = (a0 + a1) + (a2 + a3);
}

// ---------------- kB2: logits + softmax + bias + s-partials (VALU only) -----
// grid 2048 (= 32 b * 64 jc), block 256: k = tid&31, jl = tid>>5.
__global__ __launch_bounds__(256)
void kB2(const unsigned* __restrict__ u_pk, const float* __restrict__ t,
         const float* __restrict__ bias, float* __restrict__ s_part)
{
    __shared__ float lc_lds[32][33];
    __shared__ float s_lds[8][32][16];
    const int tid = threadIdx.x;
    const int k   = tid & 31;
    const int jl  = tid >> 5;
    const int b   = blockIdx.x >> 6;
    const int jc  = blockIdx.x & 63;

    float tr[16];
    const float4* tp = reinterpret_cast<const float4*>(t + ((size_t)b * KK + k) * 16);
#pragma unroll
    for (int q = 0; q < 4; ++q) {
        float4 v = tp[q];
        tr[4 * q + 0] = v.x; tr[4 * q + 1] = v.y; tr[4 * q + 2] = v.z; tr[4 * q + 3] = v.w;
    }

    uint4 ua[4], ud[4];
#pragma unroll
    for (int jj = 0; jj < 4; ++jj) {
        const int jL = jj * 8 + jl;
        const int jg = jc * 32 + jL;
        const uint4* up = reinterpret_cast<const uint4*>(u_pk)
                        + (((size_t)jg * 32 + b) * 32 + k) * 2;
        ua[jj] = up[0]; ud[jj] = up[1];
        float a0 = 0.f, a1 = 0.f;
        a0 = fmaf(bf_lo(ua[jj].x), tr[0],  a0); a1 = fmaf(bf_hi(ua[jj].x), tr[1],  a1);
        a0 = fmaf(bf_lo(ua[jj].y), tr[2],  a0); a1 = fmaf(bf_hi(ua[jj].y), tr[3],  a1);
        a0 = fmaf(bf_lo(ua[jj].z), tr[4],  a0); a1 = fmaf(bf_hi(ua[jj].z), tr[5],  a1);
        a0 = fmaf(bf_lo(ua[jj].w), tr[6],  a0); a1 = fmaf(bf_hi(ua[jj].w), tr[7],  a1);
        a0 = fmaf(bf_lo(ud[jj].x), tr[8],  a0); a1 = fmaf(bf_hi(ud[jj].x), tr[9],  a1);
        a0 = fmaf(bf_lo(ud[jj].y), tr[10], a0); a1 = fmaf(bf_hi(ud[jj].y), tr[11], a1);
        a0 = fmaf(bf_lo(ud[jj].z), tr[12], a0); a1 = fmaf(bf_hi(ud[jj].z), tr[13], a1);
        a0 = fmaf(bf_lo(ud[jj].w), tr[14], a0); a1 = fmaf(bf_hi(ud[jj].w), tr[15], a1);
        lc_lds[jL][k] = a0 + a1;
    }
    __syncthreads();

    {
        const int jq = tid >> 3, kq = tid & 7;
        float lv[4];
#pragma unroll
        for (int m = 0; m < 4; ++m) lv[m] = lc_lds[jq][kq * 4 + m];
        float pm = fmaxf(fmaxf(lv[0], lv[1]), fmaxf(lv[2], lv[3]));
        pm = fmaxf(pm, __shfl_xor(pm, 1));
        pm = fmaxf(pm, __shfl_xor(pm, 2));
        pm = fmaxf(pm, __shfl_xor(pm, 4));
        float ev[4], ps = 0.f;
#pragma unroll
        for (int m = 0; m < 4; ++m) { ev[m] = __expf((lv[m] - pm) * 0.25f); ps += ev[m]; }
        ps += __shfl_xor(ps, 1);
        ps += __shfl_xor(ps, 2);
        ps += __shfl_xor(ps, 4);
        const float inv = 1.f / ps;
        const int jg = jc * 32 + jq;
#pragma unroll
        for (int m = 0; m < 4; ++m)
            lv[m] = ev[m] * inv + bias[(size_t)(kq * 4 + m) * NN + jg];
        __syncthreads();
#pragma unroll
        for (int m = 0; m < 4; ++m) lc_lds[jq][kq * 4 + m] = lv[m];
    }
    __syncthreads();

    float sacc[16];
#pragma unroll
    for (int z = 0; z < 16; ++z) sacc[z] = 0.f;
#pragma unroll
    for (int jj = 0; jj < 4; ++jj) {
        const float cv = lc_lds[jj * 8 + jl][k];
        const uint4 a = ua[jj], d = ud[jj];
        sacc[0]  = fmaf(cv, bf_lo(a.x), sacc[0]);  sacc[1]  = fmaf(cv, bf_hi(a.x), sacc[1]);
        sacc[2]  = fmaf(cv, bf_lo(a.y), sacc[2]);  sacc[3]  = fmaf(cv, bf_hi(a.y), sacc[3]);
        sacc[4]  = fmaf(cv, bf_lo(a.z), sacc[4]);  sacc[5]  = fmaf(cv, bf_hi(a.z), sacc[5]);
        sacc[6]  = fmaf(cv, bf_lo(a.w), sacc[6]);  sacc[7]  = fmaf(cv, bf_hi(a.w), sacc[7]);
        sacc[8]  = fmaf(cv, bf_lo(d.x), sacc[8]);  sacc[9]  = fmaf(cv, bf_hi(d.x), sacc[9]);
        sacc[10] = fmaf(cv, bf_lo(d.y), sacc[10]); sacc[11] = fmaf(cv, bf_hi(d.y), sacc[11]);
        sacc[12] = fmaf(cv, bf_lo(d.z), sacc[12]); sacc[13] = fmaf(cv, bf_hi(d.z), sacc[13]);
        sacc[14] = fmaf(cv, bf_lo(d.w), sacc[14]); sacc[15] = fmaf(cv, bf_hi(d.w), sacc[15]);
    }

#pragma unroll
    for (int q = 0; q < 4; ++q)
        *reinterpret_cast<float4*>(&s_lds[jl][k][q * 4]) =
            make_float4(sacc[q * 4], sacc[q * 4 + 1], sacc[q * 4 + 2], sacc[q * 4 + 3]);
    __syncthreads();
    {
        const int kk = tid >> 3, zp = tid & 7;
        float2 o; o.x = 0.f; o.y = 0.f;
#pragma unroll
        for (int l2 = 0; l2 < 8; ++l2) {
            o.x += s_lds[l2][kk][2 * zp];
            o.y += s_lds[l2][kk][2 * zp + 1];
        }
        reinterpret_cast<float2*>(s_part)[((size_t)b * 64 + jc) * 256 + kk * 8 + zp] = o;
    }
}

// ---------------- k4: reduce jc slices + squash (float4) --------------------
__global__ __launch_bounds__(256)
void k4_squash(const float* __restrict__ s_part, float* __restrict__ out)
{
    const int idx4 = blockIdx.x * 256 + threadIdx.x;   // 4096 float4s
    const int b = idx4 >> 7, loc4 = idx4 & 127;        // loc4 = k*4 + zq
    const float4* p = reinterpret_cast<const float4*>(s_part) + (size_t)b * 8192 + loc4;
    float4 s = make_float4(0.f, 0.f, 0.f, 0.f);
#pragma unroll 8
    for (int jc = 0; jc < 64; ++jc) {
        float4 v = p[jc * 128];
        s.x += v.x; s.y += v.y; s.z += v.z; s.w += v.w;
    }
    float ss = s.x * s.x + s.y * s.y + s.z * s.z + s.w * s.w;
    ss += __shfl_xor(ss, 1);   // lanes zq 0..3 of same (b,k)
    ss += __shfl_xor(ss, 2);
    const float n = sqrtf(ss);
    const float sc = (1.f - 1.f / (__expf(n) + 1e-20f)) / (n + 1e-20f);
    float4 o; o.x = s.x * sc; o.y = s.y * sc; o.z = s.z * sc; o.w = s.w * sc;
    reinterpret_cast<float4*>(out)[idx4] = o;
}

// sentinel if workspace too small
__global__ void k_sentinel(float* __restrict__ out)
{
    out[blockIdx.x * 256 + threadIdx.x] = 12345.0f;
}

extern "C" void kernel_launch(void* const* d_in, const int* in_sizes, int n_in,
                              void* d_out, int out_size, void* d_ws, size_t ws_size,
                              hipStream_t stream)
{
    const float* x    = (const float*)d_in[0];
    const float* w    = (const float*)d_in[1];
    const float* bias = (const float*)d_in[2];
    float* out        = (float*)d_out;

    char* ws = (char*)d_ws;
    if (ws_size < WS_NEED) {
        k_sentinel<<<dim3(64), dim3(256), 0, stream>>>(out);
        return;
    }
    unsigned* u_pk   = (unsigned*)(ws + WS_U);
    float*    t_part4= (float*)(ws + WS_TP4);
    float*    t      = (float*)(ws + WS_T);
    float*    s_part = (float*)(ws + WS_SPART);

    kA3      <<<dim3(2048), dim3(256),  0, stream>>>(x, w, u_pk);
    kt_u     <<<dim3(1024), dim3(1024), 0, stream>>>(u_pk, t_part4);
    kt2b     <<<dim3(16),   dim3(256),  0, stream>>>(t_part4, t);
    kB2      <<<dim3(2048), dim3(256),  0, stream>>>(u_pk, t, bias, s_part);
    k4_squash<<<dim3(16),   dim3(256),  0, stream>>>(s_part, out);
}

// Round 13
// 65.560 us; speedup vs baseline: 1.1991x; 1.0636x over previous
//
#include <hip/hip_runtime.h>

#define NN 2048
#define KK 32

typedef __attribute__((ext_vector_type(8))) short short8;   // 8 x bf16
typedef __attribute__((ext_vector_type(4))) float f32x4;

// workspace (bytes):
//  t_part: [512 blk][32b*32k*16z] f32   32 MiB @ 0
//  s_part: [256 blk][32b*32k*16z] f32   16 MiB @ 33554432
//  tp2   : [16][16384] f32               1 MiB @ 50331648
//  sp2   : [16][16384] f32               1 MiB @ 51380224
//  t     : [32 b][32 k][16 z] f32       64 KiB @ 52428800
#define WS_TPART 0UL
#define WS_SPART 33554432UL
#define WS_TP2   50331648UL
#define WS_SP2   51380224UL
#define WS_T     52428800UL
#define WS_NEED  52494336UL

__device__ __forceinline__ short8 pack8(const float* r) {
    short8 o;
#pragma unroll
    for (int e = 0; e < 8; ++e)
        o[e] = (short)(unsigned short)((__float_as_uint(r[e]) + 0x8000u) >> 16);
    return o;
}
__device__ __forceinline__ short8 sel8(bool keep, short8 v) {
    union { short8 s; unsigned u[4]; } a, b;
    a.s = v;
#pragma unroll
    for (int i = 0; i < 4; ++i) b.u[i] = keep ? a.u[i] : 0u;
    return b.s;
}

// ---------------- kT: t partials via MFMA (R6 kA verbatim, proven) ----------
// grid 512 (4 j / block), block 512 = 8 waves; wave wv owns ck = wv*4..+4.
// A = x (rows b), B = w (cols z); C row = b (g,r), col = z (c16).
__global__ __launch_bounds__(512)
void kT(const float* __restrict__ x, const float* __restrict__ w,
        float* __restrict__ t_part)
{
    const int tid = threadIdx.x;
    const int wv = tid >> 6, l = tid & 63;
    const int z = l & 15, g = l >> 4;
    const int jl = g >> 1, ih = g & 1;
    const int j0 = blockIdx.x * 4;

    f32x4 C[4][2];
#pragma unroll
    for (int ckl = 0; ckl < 4; ++ckl)
#pragma unroll
        for (int bh = 0; bh < 2; ++bh) C[ckl][bh] = (f32x4){0.f, 0.f, 0.f, 0.f};

#pragma unroll
    for (int p = 0; p < 2; ++p) {
        const int jp = j0 + p * 2 + jl;
        short8 Af[2];
#pragma unroll
        for (int bh = 0; bh < 2; ++bh) {
            const float* xp = x + ((size_t)(bh * 16 + z) * NN + jp) * 16 + ih * 8;
            float ar[8];
            float4 v0 = *reinterpret_cast<const float4*>(xp);
            float4 v1 = *reinterpret_cast<const float4*>(xp + 4);
            ar[0]=v0.x; ar[1]=v0.y; ar[2]=v0.z; ar[3]=v0.w;
            ar[4]=v1.x; ar[5]=v1.y; ar[6]=v1.z; ar[7]=v1.w;
            Af[bh] = pack8(ar);
        }
        short8 Bf[4];
#pragma unroll
        for (int ckl = 0; ckl < 4; ++ckl) {
            const int ck = wv * 4 + ckl;
            const float* wp = w + ((size_t)ck * NN + jp) * 256 + ih * 128 + z;
            float br[8];
#pragma unroll
            for (int e = 0; e < 8; ++e) br[e] = wp[e * 16];
            Bf[ckl] = pack8(br);
        }
#pragma unroll
        for (int ckl = 0; ckl < 4; ++ckl)
#pragma unroll
            for (int bh = 0; bh < 2; ++bh)
                C[ckl][bh] = __builtin_amdgcn_mfma_f32_16x16x32_bf16(
                    Af[bh], Bf[ckl], C[ckl][bh], 0, 0, 0);
    }

    float* tp = t_part + (size_t)blockIdx.x * 16384;
#pragma unroll
    for (int ckl = 0; ckl < 4; ++ckl)
#pragma unroll
        for (int bh = 0; bh < 2; ++bh)
#pragma unroll
            for (int r = 0; r < 4; ++r)
                tp[((bh * 16 + g * 4 + r) * 32 + wv * 4 + ckl) * 16 + z] =
                    C[ckl][bh][r];
}

// ---------------- kred32: sum 32 rows of [512][16384] -> [16][16384] --------
__global__ __launch_bounds__(256)
void kred32(const float* __restrict__ src, float* __restrict__ dst)
{
    const int idx = blockIdx.x * 256 + threadIdx.x;  // 65536
    const int c4 = idx & 4095, ch = idx >> 12;
    const f32x4* P = reinterpret_cast<const f32x4*>(src);
    f32x4 a0 = (f32x4){0,0,0,0}, a1 = a0, a2 = a0, a3 = a0;
#pragma unroll 2
    for (int q = 0; q < 32; q += 4) {
        a0 += P[(size_t)(ch * 32 + q + 0) * 4096 + c4];
        a1 += P[(size_t)(ch * 32 + q + 1) * 4096 + c4];
        a2 += P[(size_t)(ch * 32 + q + 2) * 4096 + c4];
        a3 += P[(size_t)(ch * 32 + q + 3) * 4096 + c4];
    }
    reinterpret_cast<f32x4*>(dst)[(size_t)ch * 4096 + c4] = (a0 + a1) + (a2 + a3);
}

// ---------------- kred16: sum 16 rows of [256][16384] -> [16][16384] --------
__global__ __launch_bounds__(256)
void kred16(const float* __restrict__ src, float* __restrict__ dst)
{
    const int idx = blockIdx.x * 256 + threadIdx.x;  // 65536
    const int c4 = idx & 4095, ch = idx >> 12;
    const f32x4* P = reinterpret_cast<const f32x4*>(src);
    f32x4 a0 = (f32x4){0,0,0,0}, a1 = a0, a2 = a0, a3 = a0;
#pragma unroll
    for (int q = 0; q < 16; q += 4) {
        a0 += P[(size_t)(ch * 16 + q + 0) * 4096 + c4];
        a1 += P[(size_t)(ch * 16 + q + 1) * 4096 + c4];
        a2 += P[(size_t)(ch * 16 + q + 2) * 4096 + c4];
        a3 += P[(size_t)(ch * 16 + q + 3) * 4096 + c4];
    }
    reinterpret_cast<f32x4*>(dst)[(size_t)ch * 4096 + c4] = (a0 + a1) + (a2 + a3);
}

// ---------------- kt2: finish t reduce -> t[b][k][z] (f32, proven) ----------
__global__ __launch_bounds__(256)
void kt2(const float* __restrict__ tp2, float* __restrict__ t)
{
    const int c4 = blockIdx.x * 256 + threadIdx.x;   // 4096 f32x4 cols
    const f32x4* P = reinterpret_cast<const f32x4*>(tp2);
    f32x4 a0 = (f32x4){0,0,0,0}, a1 = a0, a2 = a0, a3 = a0;
#pragma unroll
    for (int q = 0; q < 16; q += 4) {
        a0 += P[(size_t)(q + 0) * 4096 + c4];
        a1 += P[(size_t)(q + 1) * 4096 + c4];
        a2 += P[(size_t)(q + 2) * 4096 + c4];
        a3 += P[(size_t)(q + 3) * 4096 + c4];
    }
    reinterpret_cast<f32x4*>(t)[c4] = (a0 + a1) + (a2 + a3);
}

// ---------------- kBF: fused recompute-u + logits + softmax + s -------------
// grid 256 (8 j / block), block 512 = 8 waves; wave wv owns k = wv*4..+4.
// u recompute: A = w (M=z), B = x (N=b) masked per j (R8-proven fragments);
// C row = z = g*4+r (regs), col = b = c16 (lanes). u stays in registers.
// logit: 4 FMA vs t_lds + shfl_xor(16,32) over g-lanes; softmax = kB2 mapping.
__global__ __launch_bounds__(512)
void kBF(const float* __restrict__ x, const float* __restrict__ w,
         const float* __restrict__ t, const float* __restrict__ bias,
         float* __restrict__ s_part)
{
    __shared__ float t_lds[32 * 520];   // [b][520] pad (66.6 KB)
    __shared__ float l_lds[32][33];
    __shared__ float c_lds[32][33];
    __shared__ float b_lds[32][8];
    const int tid = threadIdx.x;
    const int wv = tid >> 6, l = tid & 63;
    const int c16 = l & 15, g = l >> 4;
    const int jl = g >> 1, ih = g & 1;
    const int j0 = blockIdx.x * 8;

    // stage t (f32) + bias
    {
        const f32x4* tg = reinterpret_cast<const f32x4*>(t);
#pragma unroll
        for (int q = 0; q < 8; ++q) {
            const int idx4 = q * 512 + tid;
            const int b = idx4 >> 7, col4 = idx4 & 127;
            *reinterpret_cast<f32x4*>(&t_lds[b * 520 + col4 * 4]) = tg[idx4];
        }
        if (tid < 256)
            b_lds[tid >> 3][tid & 7] = bias[(size_t)(tid >> 3) * NN + j0 + (tid & 7)];
    }
    __syncthreads();

    f32x4 S[4][2];
#pragma unroll
    for (int ckl = 0; ckl < 4; ++ckl)
#pragma unroll
        for (int bn = 0; bn < 2; ++bn) S[ckl][bn] = (f32x4){0.f, 0.f, 0.f, 0.f};

#pragma unroll 1
    for (int p = 0; p < 4; ++p) {
        const int jp = j0 + p * 2 + jl;

        short8 Wf[4];
#pragma unroll
        for (int ckl = 0; ckl < 4; ++ckl) {
            const int k = wv * 4 + ckl;
            const float* wp = w + ((size_t)k * NN + jp) * 256 + ih * 128 + c16;
            float br[8];
#pragma unroll
            for (int e = 0; e < 8; ++e) br[e] = wp[e * 16];
            Wf[ckl] = pack8(br);
        }
        short8 Xf[2];
#pragma unroll
        for (int bn = 0; bn < 2; ++bn) {
            const float* xp = x + ((size_t)(bn * 16 + c16) * NN + jp) * 16 + ih * 8;
            float ar[8];
            float4 v0 = *reinterpret_cast<const float4*>(xp);
            float4 v1 = *reinterpret_cast<const float4*>(xp + 4);
            ar[0]=v0.x; ar[1]=v0.y; ar[2]=v0.z; ar[3]=v0.w;
            ar[4]=v1.x; ar[5]=v1.y; ar[6]=v1.z; ar[7]=v1.w;
            Xf[bn] = pack8(ar);
        }

#pragma unroll 1
        for (int jj = 0; jj < 2; ++jj) {
            const bool keep = (jl == jj);
            const f32x4 zero = (f32x4){0.f, 0.f, 0.f, 0.f};

            // u recompute (kept alive in C) + logits
            f32x4 C[4][2];
#pragma unroll
            for (int ckl = 0; ckl < 4; ++ckl) {
                const short8 wsel = sel8(keep, Wf[ckl]);
                const int k = wv * 4 + ckl;
#pragma unroll
                for (int bn = 0; bn < 2; ++bn) {
                    C[ckl][bn] = __builtin_amdgcn_mfma_f32_16x16x32_bf16(
                        wsel, Xf[bn], zero, 0, 0, 0);
                    const int b = bn * 16 + c16;
                    const f32x4 tv = *reinterpret_cast<const f32x4*>(
                        &t_lds[b * 520 + k * 16 + g * 4]);
                    float pv = C[ckl][bn][0] * tv[0] + C[ckl][bn][1] * tv[1]
                             + C[ckl][bn][2] * tv[2] + C[ckl][bn][3] * tv[3];
                    pv += __shfl_xor(pv, 16);
                    pv += __shfl_xor(pv, 32);
                    if (g == 0) l_lds[b][k] = pv;
                }
            }
            __syncthreads();

            // softmax over k (32): threads = 32 b x 16 kq, 2 k each
            {
                const int bb = tid >> 4, kq = tid & 15;
                const float lv0 = l_lds[bb][2 * kq];
                const float lv1 = l_lds[bb][2 * kq + 1];
                float m = fmaxf(lv0, lv1);
                m = fmaxf(m, __shfl_xor(m, 1));
                m = fmaxf(m, __shfl_xor(m, 2));
                m = fmaxf(m, __shfl_xor(m, 4));
                m = fmaxf(m, __shfl_xor(m, 8));
                const float e0 = __expf((lv0 - m) * 0.25f);
                const float e1 = __expf((lv1 - m) * 0.25f);
                float sum = e0 + e1;
                sum += __shfl_xor(sum, 1);
                sum += __shfl_xor(sum, 2);
                sum += __shfl_xor(sum, 4);
                sum += __shfl_xor(sum, 8);
                const float inv = 1.f / sum;
                const int jloc = p * 2 + jj;
                c_lds[bb][2 * kq]     = e0 * inv + b_lds[2 * kq][jloc];
                c_lds[bb][2 * kq + 1] = e1 * inv + b_lds[2 * kq + 1][jloc];
            }
            __syncthreads();

            // s accumulation from register-held u
#pragma unroll
            for (int ckl = 0; ckl < 4; ++ckl) {
                const int k = wv * 4 + ckl;
#pragma unroll
                for (int bn = 0; bn < 2; ++bn) {
                    const float cv = c_lds[bn * 16 + c16][k];
#pragma unroll
                    for (int r = 0; r < 4; ++r)
                        S[ckl][bn][r] = fmaf(cv, C[ckl][bn][r], S[ckl][bn][r]);
                }
            }
        }
    }

    float* sp = s_part + (size_t)blockIdx.x * 16384;
#pragma unroll
    for (int ckl = 0; ckl < 4; ++ckl) {
        const int k = wv * 4 + ckl;
#pragma unroll
        for (int bn = 0; bn < 2; ++bn)
            *reinterpret_cast<f32x4*>(
                &sp[(bn * 16 + c16) * 512 + k * 16 + g * 4]) = S[ckl][bn];
    }
}

// ---------------- ksq: reduce 16 s-chunks + squash (R6 ks2, proven) ---------
__global__ __launch_bounds__(256)
void ksq(const float* __restrict__ sp2, float* __restrict__ out)
{
    const int c4 = blockIdx.x * 256 + threadIdx.x;   // 4096 = b*128 + k*4 + zq
    const f32x4* P = reinterpret_cast<const f32x4*>(sp2);
    f32x4 a0 = (f32x4){0,0,0,0}, a1 = a0, a2 = a0, a3 = a0;
#pragma unroll
    for (int q = 0; q < 16; q += 4) {
        a0 += P[(size_t)(q + 0) * 4096 + c4];
        a1 += P[(size_t)(q + 1) * 4096 + c4];
        a2 += P[(size_t)(q + 2) * 4096 + c4];
        a3 += P[(size_t)(q + 3) * 4096 + c4];
    }
    f32x4 s = (a0 + a1) + (a2 + a3);
    float ss = s.x * s.x + s.y * s.y + s.z * s.z + s.w * s.w;
    ss += __shfl_xor(ss, 1);
    ss += __shfl_xor(ss, 2);
    const float n = sqrtf(ss);
    const float sc = (1.f - 1.f / (__expf(n) + 1e-20f)) / (n + 1e-20f);
    f32x4 o; o.x = s.x * sc; o.y = s.y * sc; o.z = s.z * sc; o.w = s.w * sc;
    reinterpret_cast<f32x4*>(out)[c4] = o;
}

// sentinel if workspace too small
__global__ void k_sentinel(float* __restrict__ out)
{
    out[blockIdx.x * 256 + threadIdx.x] = 12345.0f;
}

extern "C" void kernel_launch(void* const* d_in, const int* in_sizes, int n_in,
                              void* d_out, int out_size, void* d_ws, size_t ws_size,
                              hipStream_t stream)
{
    const float* x    = (const float*)d_in[0];
    const float* w    = (const float*)d_in[1];
    const float* bias = (const float*)d_in[2];
    float* out        = (float*)d_out;

    char* ws = (char*)d_ws;
    if (ws_size < WS_NEED) {
        k_sentinel<<<dim3(64), dim3(256), 0, stream>>>(out);
        return;
    }
    float* t_part = (float*)(ws + WS_TPART);
    float* s_part = (float*)(ws + WS_SPART);
    float* tp2    = (float*)(ws + WS_TP2);
    float* sp2    = (float*)(ws + WS_SP2);
    float* t      = (float*)(ws + WS_T);

    kT    <<<dim3(512), dim3(512), 0, stream>>>(x, w, t_part);
    kred32<<<dim3(256), dim3(256), 0, stream>>>(t_part, tp2);
    kt2   <<<dim3(16),  dim3(256), 0, stream>>>(tp2, t);
    kBF   <<<dim3(256), dim3(512), 0, stream>>>(x, w, t, bias, s_part);
    kred16<<<dim3(256), dim3(256), 0, stream>>>(s_part, sp2);
    ksq   <<<dim3(16),  dim3(256), 0, stream>>>(sp2, out);
}